// Round 3
// baseline (538.799 us; speedup 1.0000x reference)
//
#include <hip/hip_runtime.h>
#include <hip/hip_bf16.h>
#include <stdint.h>

// Problem constants
#define B_    16
#define CIN   256
#define COUT  256
#define E_    8
#define HW    1024   // 32x32
#define PH    34     // padded H (zero halo)
#define PW    34

typedef __attribute__((ext_vector_type(8))) short  short8;
typedef __attribute__((ext_vector_type(4))) float  floatx4;

// Workspace layout (bytes):
//   [0,64)      : decisions int[16]
//   [64,16448)  : pooled float[16*256]  (SUMS, not means; decide scales)
//   [XT_OFF,..) : xt bf16 [16][34][34][256]  (padded NHWC, zero halo)
//   [WT_OFF,..) : wt bf16 [8][9][256][256]   ([e][r*3+s][co][ci])
#define XT_OFF 17408
#define XT_BYTES (B_*PH*PW*CIN*2)               // 9,469,952
#define WT_OFF (XT_OFF + XT_BYTES)

// async global->LDS, 16B per lane. LDS dest is wave-uniform base + lane*16.
__device__ __forceinline__ void gld_lds16(const void* g, void* l) {
    __builtin_amdgcn_global_load_lds(
        (const __attribute__((address_space(1))) unsigned int*)g,
        (__attribute__((address_space(3))) unsigned int*)l,
        16, 0, 0);
}

// ---------------- Kernel 1: x NCHW fp32 -> padded NHWC bf16, fused global-avg-pool ----------------
__global__ void xpose_kernel(const float* __restrict__ x, unsigned short* __restrict__ xt,
                             float* __restrict__ pooled) {
    // grid (16, 32, 8): b, hw-tile (32 hw), ci-tile (32 ci); 256 threads
    int b = blockIdx.x;
    int hw0 = blockIdx.y * 32;
    int ci0 = blockIdx.z * 32;
    __shared__ float tile[32][33];
    int t = threadIdx.x;
    int j = t & 31;      // hw within tile (read phase)
    int i = t >> 5;      // ci sub-row 0..7
    #pragma unroll
    for (int p = 0; p < 4; ++p)
        tile[i + p*8][j] = x[((size_t)b*CIN + ci0 + i + p*8)*HW + hw0 + j];
    __syncthreads();
    // fused pool: thread t<32 sums its ci row over the 32 hw of this tile.
    if (t < 32) {
        float s = 0.0f;
        #pragma unroll
        for (int q = 0; q < 32; ++q) s += tile[t][q];
        atomicAdd(&pooled[b*CIN + ci0 + t], s);   // pooled pre-zeroed by memset
    }
    // write phase: 128 threads, each packs 8 consecutive ci -> one 16B store
    if (t < 128) {
        int g = t & 3;              // ci group of 8 (0..3)
        int hwl = t >> 2;           // hw within tile (0..31)
        int hw = hw0 + hwl;
        int h = hw >> 5, w = hw & 31;
        short8 v;
        #pragma unroll
        for (int q = 0; q < 8; ++q) {
            __hip_bfloat16 hv = __float2bfloat16(tile[g*8 + q][hwl]);
            v[q] = *(short*)&hv;
        }
        *(short8*)&xt[(((size_t)b*PH + h + 1)*PW + (w + 1))*CIN + ci0 + g*8] = v;
    }
}

// ---------------- Kernel 2: logits + argmax -> decisions ----------------
__global__ void decide_kernel(const float* __restrict__ pooled, const float* __restrict__ wc,
                              const float* __restrict__ bc, int* __restrict__ dec) {
    int t = threadIdx.x;          // 128 threads: b = t/8, e = t%8
    int b = t >> 3, e = t & 7;
    float acc = 0.0f;
    const float4* pp = (const float4*)(pooled + b*CIN);
    const float4* ww = (const float4*)(wc + e*CIN);
    #pragma unroll 4
    for (int i = 0; i < CIN/4; ++i) {
        float4 p = pp[i], w = ww[i];
        acc += p.x*w.x + p.y*w.y + p.z*w.z + p.w*w.w;
    }
    acc = acc * (1.0f/1024.0f) + bc[e];   // pooled holds sums; mean = sum/1024
    __shared__ float lg[16][8];
    lg[b][e] = acc;
    __syncthreads();
    if (e == 0) {
        float best = lg[b][0]; int bi = 0;
        #pragma unroll
        for (int j = 1; j < 8; ++j) { if (lg[b][j] > best) { best = lg[b][j]; bi = j; } }
        dec[b] = bi;
    }
}

// ---------------- Kernel 3: we [e][co][ci][3][3] fp32 -> wt [e][rs][co][ci] bf16 ----------------
__global__ void wpose_kernel(const float* __restrict__ we, unsigned short* __restrict__ wt) {
    int e = blockIdx.x >> 8, co = blockIdx.x & 255;
    __shared__ float buf[CIN*9];
    const float* src = we + ((size_t)e*COUT + co)*CIN*9;
    int t = threadIdx.x;
    #pragma unroll
    for (int k = 0; k < 9; ++k) buf[t + k*256] = src[t + k*256];
    __syncthreads();
    for (int idx = t; idx < 288; idx += 256) {
        int rs = idx >> 5, grp = idx & 31;
        short8 v;
        #pragma unroll
        for (int q = 0; q < 8; ++q) {
            __hip_bfloat16 h = __float2bfloat16(buf[(grp*8 + q)*9 + rs]);
            v[q] = *(short*)&h;
        }
        *(short8*)&wt[(((size_t)e*9 + rs)*COUT + co)*CIN + grp*8] = v;
    }
}

// ---------------- Kernel 4: shift-decomposed implicit-GEMM conv + gather-write ----------------
// Big-tile redesign: per-WAVE output 128co x 64hw (acc = 128 AGPRs) -> 44 FLOP per
// LDS byte (was 32) and 32 MFMA per wave-iteration (was 16), raising the LDS-BW
// ceiling on MfmaUtil from ~60% to ~83% and halving barriers per FLOP.
// Block = 4 waves = 128co x 256hw.  2 blocks/CU (reg-bound: 128 AGPR + <=128 arch).
// sA 3-deep distance-2 counted-vmcnt prefetch; sB double-buffered, staged at sh==7.
// grid: x = mt*4+ht (2 co-halves x 4 hw-quarters), y = b (16), z = e (8); 256 threads
__global__ __launch_bounds__(256, 2) void conv_kernel(
    const unsigned short* __restrict__ xt, const unsigned short* __restrict__ wt,
    const float* __restrict__ be, const int* __restrict__ dec,
    float* __restrict__ out) {

    int mt = blockIdx.x >> 2, ht = blockIdx.x & 3;
    int b = blockIdx.y;
    int e = blockIdx.z;

    // volatile reads: compute 'active' without keeping dec[16] live in registers
    bool active = false;
    {
        const volatile int* dv = (const volatile int*)dec;
        #pragma unroll
        for (int i = 0; i < 16; ++i) active |= (dv[i] == e);
    }
    if (!active) return;   // uniform across block

    // Chunk-addressed LDS (16 B chunks), XOR-swizzled: global chunk (row, g)
    // lives at LDS chunk row*4 + (g ^ ((row>>1)&3)).  XOR is involutive.
    // sA[3]: 512 chunks each (128 co x 4 ci-chunks), 8 KB each -> 24 KB.
    // sB[2]: 1536 chunks each (1360 live: 10x34 halo rows x 4 ci-chunks; rest is
    //        dead padding so staging is a uniform 6 loads/thread) -> 48 KB.
    // Total 72 KB -> 2 blocks/CU (matches the register-bound occupancy).
    __shared__ __align__(16) unsigned short sA[3][512*8];
    __shared__ __align__(16) unsigned short sB[2][1536*8];

    int t = threadIdx.x;
    int w = t >> 6, lane = t & 63;
    int kg = lane >> 4, ln = lane & 15;

    int ph0 = ht * 8;       // padded halo start row (10 rows: 8 out + 2 halo)
    int co0 = mt * 128;

    floatx4 acc[4][8];      // [im: hw 16-row group][jn: co 16-col group]
    #pragma unroll
    for (int i = 0; i < 4; ++i)
        #pragma unroll
        for (int j = 0; j < 8; ++j) acc[i][j] = (floatx4)0.0f;

    const unsigned short* xb = xt + ((size_t)b*PH + ph0)*PW*CIN;   // halo base (10x34 rows)
    const unsigned short* wb = wt + (size_t)e*9*COUT*CIN + (size_t)co0*CIN;

    // ---- staging helpers (16 B/lane, lane-linear LDS dest, swizzled source) ----
    // stageA: 2 loads/thread.  stageB: 6 loads/thread (uniform; c>=1360 src-clamped,
    // dest lands in sB dead padding).
    auto stageA = [&](int ck, int sh, int buf) {
        const unsigned short* wsrc = wb + (size_t)sh*COUT*CIN + ck*32;
        #pragma unroll
        for (int k = 0; k < 2; ++k) {
            int c = t + k*256;
            int row = c >> 2, gs = c & 3;
            int g = gs ^ ((row >> 1) & 3);
            gld_lds16(wsrc + (size_t)row*CIN + g*8, &sA[buf][c*8]);
        }
    };
    auto stageB = [&](int ck, int buf) {
        const unsigned short* xsrc = xb + ck*32;
        #pragma unroll
        for (int k = 0; k < 6; ++k) {
            int c = t + k*256;
            int cc = c < 1360 ? c : 1359;      // clamp SOURCE only; dest stays lane-linear
            int rB = cc >> 2, gs = cc & 3;
            int g = gs ^ ((rB >> 1) & 3);
            gld_lds16(xsrc + (size_t)rB*CIN + g*8, &sB[buf][c*8]);
        }
    };

    // ---- prologue: B(ck0) [6], A(it0) [2], A(it1) [2]; keep A(it1) in flight ----
    stageB(0, 0);
    stageA(0, 0, 0);
    stageA(0, 1, 1);
    asm volatile("s_waitcnt vmcnt(2)" ::: "memory");
    __builtin_amdgcn_s_barrier();

    // ---- main loop: it = ck*9+sh; read sA[it%3], sB[ck&1] ----
    // Per-wave FIFO ledger at end of iter it (issue order: A then B):
    //   normal:  [A(it+1):2][A(it+2):2]            -> vmcnt(2)
    //   sh==7:   [A(it+1):2][A(it+2):2][B(next):6] -> vmcnt(8)
    //   sh==8:   [A(next0):2][B:6][A(next1):2]     -> vmcnt(2)  (drains A(next0)+B)
    //   no-issue tail:                              -> vmcnt(0)
    for (int ck = 0; ck < 8; ++ck) {
        int bb = ck & 1;
        for (int sh = 0; sh < 9; ++sh) {
            int it = ck*9 + sh;
            int ab = it % 3;
            int r = sh / 3, s = sh - r*3;
            bool doA = (it + 2 < 72);
            bool doB = (sh == 7) && (ck < 7);

            if (doA) { int nit = it + 2; int nck = nit/9; stageA(nck, nit - nck*9, nit % 3); }
            if (doB) stageB(ck + 1, bb ^ 1);

            // frag reads (swizzled).  a[jn]: co side (all 128 co); bv[im]: hw side (wave's 64 hw)
            short8 a[8], bv[4];
            #pragma unroll
            for (int jn = 0; jn < 8; ++jn) {
                int row = jn*16 + ln;
                int cL = row*4 + (kg ^ ((row >> 1) & 3));
                a[jn] = *(const short8*)(&sA[ab][cL*8]);
            }
            #pragma unroll
            for (int im = 0; im < 4; ++im) {
                int n  = w*64 + im*16 + ln;
                int hl = n >> 5, wl = n & 31;
                int rB = (hl + r)*34 + (wl + s);
                int cL = rB*4 + (kg ^ ((rB >> 1) & 3));
                bv[im] = *(const short8*)(&sB[bb][cL*8]);
            }

            // swapped operands: C rows = hw (bv), cols = co (a)
            __builtin_amdgcn_s_setprio(1);
            #pragma unroll
            for (int im = 0; im < 4; ++im)
                #pragma unroll
                for (int jn = 0; jn < 8; ++jn)
                    acc[im][jn] = __builtin_amdgcn_mfma_f32_16x16x32_bf16(bv[im], a[jn], acc[im][jn], 0, 0, 0);
            __builtin_amdgcn_s_setprio(0);

            if (it != 71) {
                if (doB)      asm volatile("s_waitcnt vmcnt(8) lgkmcnt(0)" ::: "memory");
                else if (doA) asm volatile("s_waitcnt vmcnt(2) lgkmcnt(0)" ::: "memory");
                else          asm volatile("s_waitcnt vmcnt(0) lgkmcnt(0)" ::: "memory");
                __builtin_amdgcn_s_barrier();
            }
        }
    }

    // ---- epilogue: bias + relu.  Layout: col(ln)=co, row(kg*4+rg)=hw ----
    float bias[8];
    #pragma unroll
    for (int jn = 0; jn < 8; ++jn)
        bias[jn] = be[e*COUT + co0 + jn*16 + ln];
    #pragma unroll
    for (int im = 0; im < 4; ++im)
        #pragma unroll
        for (int jn = 0; jn < 8; ++jn)
            #pragma unroll
            for (int rg = 0; rg < 4; ++rg) {
                float v = acc[im][jn][rg] + bias[jn];
                acc[im][jn][rg] = v > 0.0f ? v : 0.0f;
            }

    // ---- write to every output slot i with dec[i]==e: float4 stores along hw ----
    const volatile int* dv = (const volatile int*)dec;
    for (int i = 0; i < 16; ++i) {
        if (dv[i] != e) continue;
        float* ob = out + (size_t)(i*16 + b)*COUT*HW;
        #pragma unroll
        for (int jn = 0; jn < 8; ++jn) {
            int co = co0 + jn*16 + ln;
            float* orow = ob + (size_t)co*HW + ht*256 + w*64 + kg*4;
            #pragma unroll
            for (int im = 0; im < 4; ++im)
                *(floatx4*)(orow + im*16) = acc[im][jn];
        }
    }
}

extern "C" void kernel_launch(void* const* d_in, const int* in_sizes, int n_in,
                              void* d_out, int out_size, void* d_ws, size_t ws_size,
                              hipStream_t stream) {
    const float* x  = (const float*)d_in[0];
    const float* wc = (const float*)d_in[1];
    const float* bc = (const float*)d_in[2];
    const float* we = (const float*)d_in[3];
    const float* be = (const float*)d_in[4];
    float* out = (float*)d_out;

    char* ws = (char*)d_ws;
    int*   dec    = (int*)ws;
    float* pooled = (float*)(ws + 64);
    unsigned short* xt = (unsigned short*)(ws + XT_OFF);
    unsigned short* wt = (unsigned short*)(ws + WT_OFF);

    // single memset: zeroes dec (overwritten), pooled (accumulated into), and xt halo
    hipMemsetAsync(ws, 0, XT_OFF + XT_BYTES, stream);

    xpose_kernel <<<dim3(16, 32, 8), 256, 0, stream>>>(x, xt, pooled);
    wpose_kernel <<<2048, 256, 0, stream>>>(we, wt);
    decide_kernel<<<1, 128, 0, stream>>>(pooled, wc, bc, dec);
    conv_kernel  <<<dim3(8, 16, 8), 256, 0, stream>>>(xt, wt, be, dec, out);
}

// Round 4
// 531.163 us; speedup vs baseline: 1.0144x; 1.0144x over previous
//
#include <hip/hip_runtime.h>
#include <hip/hip_bf16.h>
#include <stdint.h>

// Problem constants
#define B_    16
#define CIN   256
#define COUT  256
#define E_    8
#define HW    1024   // 32x32
#define PH    34     // padded H (zero halo)
#define PW    34

typedef __attribute__((ext_vector_type(8))) short  short8;
typedef __attribute__((ext_vector_type(4))) float  floatx4;

// Workspace layout (bytes):
//   [0,64)      : decisions int[16]
//   [64,16448)  : pooled float[16*256]  (SUMS, not means; decide scales)
//   [XT_OFF,..) : xt bf16 [16][34][34][256]  (padded NHWC, zero halo)
//   [WT_OFF,..) : wt bf16 [8][9][256][256]   ([e][r*3+s][co][ci])
#define XT_OFF 17408
#define XT_BYTES (B_*PH*PW*CIN*2)               // 9,469,952
#define WT_OFF (XT_OFF + XT_BYTES)

// async global->LDS, 16B per lane. LDS dest is wave-uniform base + lane*16.
__device__ __forceinline__ void gld_lds16(const void* g, void* l) {
    __builtin_amdgcn_global_load_lds(
        (const __attribute__((address_space(1))) unsigned int*)g,
        (__attribute__((address_space(3))) unsigned int*)l,
        16, 0, 0);
}

// ---------------- Kernel 1: x NCHW fp32 -> padded NHWC bf16, fused global-avg-pool ----------------
__global__ void xpose_kernel(const float* __restrict__ x, unsigned short* __restrict__ xt,
                             float* __restrict__ pooled) {
    // grid (16, 32, 8): b, hw-tile (32 hw), ci-tile (32 ci); 256 threads
    int b = blockIdx.x;
    int hw0 = blockIdx.y * 32;
    int ci0 = blockIdx.z * 32;
    __shared__ float tile[32][33];
    int t = threadIdx.x;
    int j = t & 31;      // hw within tile (read phase)
    int i = t >> 5;      // ci sub-row 0..7
    #pragma unroll
    for (int p = 0; p < 4; ++p)
        tile[i + p*8][j] = x[((size_t)b*CIN + ci0 + i + p*8)*HW + hw0 + j];
    __syncthreads();
    // fused pool: thread t<32 sums its ci row over the 32 hw of this tile.
    if (t < 32) {
        float s = 0.0f;
        #pragma unroll
        for (int q = 0; q < 32; ++q) s += tile[t][q];
        atomicAdd(&pooled[b*CIN + ci0 + t], s);   // pooled pre-zeroed by memset
    }
    // write phase: 128 threads, each packs 8 consecutive ci -> one 16B store
    if (t < 128) {
        int g = t & 3;              // ci group of 8 (0..3)
        int hwl = t >> 2;           // hw within tile (0..31)
        int hw = hw0 + hwl;
        int h = hw >> 5, w = hw & 31;
        short8 v;
        #pragma unroll
        for (int q = 0; q < 8; ++q) {
            __hip_bfloat16 hv = __float2bfloat16(tile[g*8 + q][hwl]);
            v[q] = *(short*)&hv;
        }
        *(short8*)&xt[(((size_t)b*PH + h + 1)*PW + (w + 1))*CIN + ci0 + g*8] = v;
    }
}

// ---------------- Kernel 2: logits + argmax -> decisions ----------------
__global__ void decide_kernel(const float* __restrict__ pooled, const float* __restrict__ wc,
                              const float* __restrict__ bc, int* __restrict__ dec) {
    int t = threadIdx.x;          // 128 threads: b = t/8, e = t%8
    int b = t >> 3, e = t & 7;
    float acc = 0.0f;
    const float4* pp = (const float4*)(pooled + b*CIN);
    const float4* ww = (const float4*)(wc + e*CIN);
    #pragma unroll 4
    for (int i = 0; i < CIN/4; ++i) {
        float4 p = pp[i], w = ww[i];
        acc += p.x*w.x + p.y*w.y + p.z*w.z + p.w*w.w;
    }
    acc = acc * (1.0f/1024.0f) + bc[e];   // pooled holds sums; mean = sum/1024
    __shared__ float lg[16][8];
    lg[b][e] = acc;
    __syncthreads();
    if (e == 0) {
        float best = lg[b][0]; int bi = 0;
        #pragma unroll
        for (int j = 1; j < 8; ++j) { if (lg[b][j] > best) { best = lg[b][j]; bi = j; } }
        dec[b] = bi;
    }
}

// ---------------- Kernel 3: we [e][co][ci][3][3] fp32 -> wt [e][rs][co][ci] bf16 ----------------
__global__ void wpose_kernel(const float* __restrict__ we, unsigned short* __restrict__ wt) {
    int e = blockIdx.x >> 8, co = blockIdx.x & 255;
    __shared__ float buf[CIN*9];
    const float* src = we + ((size_t)e*COUT + co)*CIN*9;
    int t = threadIdx.x;
    #pragma unroll
    for (int k = 0; k < 9; ++k) buf[t + k*256] = src[t + k*256];
    __syncthreads();
    for (int idx = t; idx < 288; idx += 256) {
        int rs = idx >> 5, grp = idx & 31;
        short8 v;
        #pragma unroll
        for (int q = 0; q < 8; ++q) {
            __hip_bfloat16 h = __float2bfloat16(buf[(grp*8 + q)*9 + rs]);
            v[q] = *(short*)&h;
        }
        *(short8*)&wt[(((size_t)e*9 + rs)*COUT + co)*CIN + grp*8] = v;
    }
}

// ---------------- Kernel 4: 8-wave phase-interleaved implicit-GEMM conv (m201-template port) ----
// Block = 512 threads / 8 waves (2 co-halves x 4 hw-quarters); block tile 256co x 256hw;
// per-wave 128co x 64hw (acc[4][8] = 128 AGPR).  Per K=32 iteration: 2 phases, each
// {1 gld_lds stage || 4-8 ds_reads -> barrier -> setprio(1) -> 16 MFMA -> setprio(0) ->
// barrier}.  sA 3-deep distance-2 prefetch, counted vmcnt(2/3) per iteration (never 0
// mid-loop); sB double-buffered, staged 1/3-per-iteration at sh=5,6,7.
// Per-phase frag reads keep live arch regs low (a[0..3] dead after ph0): avoids R3's spill.
// grid: x = ht (4 hw-quarters, 8 output rows each), y = b (16), z = e (8); 512 threads
__global__ __launch_bounds__(512, 2) void conv_kernel(
    const unsigned short* __restrict__ xt, const unsigned short* __restrict__ wt,
    const float* __restrict__ be, const int* __restrict__ dec,
    float* __restrict__ out) {

    int ht = blockIdx.x;
    int b = blockIdx.y;
    int e = blockIdx.z;

    // volatile reads: compute 'active' without keeping dec[16] live in registers
    bool active = false;
    {
        const volatile int* dv = (const volatile int*)dec;
        #pragma unroll
        for (int i = 0; i < 16; ++i) active |= (dv[i] == e);
    }
    if (!active) return;   // uniform across block

    // Chunk-addressed LDS (16 B chunks), XOR-swizzled: global chunk (row, g) lives at
    // LDS chunk row*4 + (g ^ ((row>>1)&3)).  Involutive.
    // sA[3]: 1024 chunks each (256 co x 4 ci-chunks of 8), 16 KB each -> 48 KB.
    // sB[2]: 1536 chunks each (1360 live: 10x34 halo rows x 4 ci-chunks), 24 KB -> 48 KB.
    // Total 96 KB; 1 block/CU (8 waves, 2/SIMD -- reg budget 256/thread).
    __shared__ __align__(16) unsigned short sA[3][1024*8];
    __shared__ __align__(16) unsigned short sB[2][1536*8];

    int t = threadIdx.x;
    int wave = t >> 6, lane = t & 63;
    int wm = wave >> 2, wn = wave & 3;     // co half (128), hw quarter (64)
    int kg = lane >> 4, ln = lane & 15;

    int ph0 = ht * 8;       // padded halo start row (10 rows: 8 out + 2 halo)

    floatx4 acc[4][8];      // [im: hw 16-row group][jn: co 16-col group]
    #pragma unroll
    for (int i = 0; i < 4; ++i)
        #pragma unroll
        for (int j = 0; j < 8; ++j) acc[i][j] = (floatx4)0.0f;

    const unsigned short* xb = xt + ((size_t)b*PH + ph0)*PW*CIN;   // halo base (10x34 rows)
    const unsigned short* wb = wt + (size_t)e*9*COUT*CIN;          // full 256-co A

    // ---- staging: single gld_lds call per thread per invocation ----
    auto stageA1 = [&](int ck, int sh, int buf, int k) {   // 512 chunks per call, 2 calls/tile
        const unsigned short* wsrc = wb + (size_t)sh*COUT*CIN + ck*32;
        int c = t + k*512;
        int row = c >> 2, gs = c & 3;
        int g = gs ^ ((row >> 1) & 3);
        gld_lds16(wsrc + (size_t)row*CIN + g*8, &sA[buf][c*8]);
    };
    auto stageB1 = [&](int ck, int buf, int j) {           // 512 chunks per call, 3 calls/tile
        const unsigned short* xsrc = xb + ck*32;
        int c = t + j*512;
        int cc = c < 1360 ? c : 1359;      // clamp SOURCE only; dest stays lane-linear
        int rB = cc >> 2, gs = cc & 3;
        int g = gs ^ ((rB >> 1) & 3);
        gld_lds16(xsrc + (size_t)rB*CIN + g*8, &sB[buf][c*8]);
    };

    // ---- prologue: B(ck0) x3, A(it0) x2 -> buf0, A(it1) x2 -> buf1 ----
    stageB1(0, 0, 0); stageB1(0, 0, 1); stageB1(0, 0, 2);
    stageA1(0, 0, 0, 0); stageA1(0, 0, 0, 1);
    stageA1(0, 1, 1, 0); stageA1(0, 1, 1, 1);
    asm volatile("s_waitcnt vmcnt(2)" ::: "memory");   // B+A(it0) done; A(it1) in flight
    __builtin_amdgcn_s_barrier();

    // ---- main loop: it = ck*9+sh; read sA[it%3], sB[ck&1]; stage A(it+2), B thirds ----
    // Per-wave FIFO ledger at end of it (issue order: ph0{A2_0, B?}, ph1{A2_1}):
    //   outstanding-after-A(it+1) = issued-during-it = 2 + (B?1:0) -> vmcnt(3|2|0).
    for (int ck = 0; ck < 8; ++ck) {
        int bb = ck & 1;
        for (int sh = 0; sh < 9; ++sh) {
            int it = ck*9 + sh;
            int ab = it % 3;
            int r = sh / 3, s = sh - r*3;
            bool doA = (it + 2 < 72);
            int nit = it + 2, nck = nit/9, nsh = nit - nck*9, nb = nit % 3;
            bool doB = (sh >= 5) && (sh <= 7) && (ck < 7);

            // ================= phase 0 =================
            if (doA) stageA1(nck, nsh, nb, 0);
            if (doB) stageB1(ck + 1, bb ^ 1, sh - 5);
            short8 bv[4], af[4];
            #pragma unroll
            for (int im = 0; im < 4; ++im) {               // hw-side frags (live both phases)
                int n  = wn*64 + im*16 + ln;
                int hl = n >> 5, wl = n & 31;
                int rB = (hl + r)*34 + (wl + s);
                int cL = rB*4 + (kg ^ ((rB >> 1) & 3));
                bv[im] = *(const short8*)(&sB[bb][cL*8]);
            }
            #pragma unroll
            for (int jn = 0; jn < 4; ++jn) {               // co frags jn 0..3
                int row = wm*128 + jn*16 + ln;
                int cL = row*4 + (kg ^ ((row >> 1) & 3));
                af[jn] = *(const short8*)(&sA[ab][cL*8]);
            }
            __builtin_amdgcn_s_barrier();
            __builtin_amdgcn_s_setprio(1);
            #pragma unroll
            for (int im = 0; im < 4; ++im)
                #pragma unroll
                for (int jn = 0; jn < 4; ++jn)
                    acc[im][jn] = __builtin_amdgcn_mfma_f32_16x16x32_bf16(bv[im], af[jn], acc[im][jn], 0, 0, 0);
            __builtin_amdgcn_s_setprio(0);
            __builtin_amdgcn_s_barrier();

            // ================= phase 1 =================
            if (doA) stageA1(nck, nsh, nb, 1);
            #pragma unroll
            for (int jn = 0; jn < 4; ++jn) {               // co frags jn 4..7 (reuse af regs)
                int row = wm*128 + (jn + 4)*16 + ln;
                int cL = row*4 + (kg ^ ((row >> 1) & 3));
                af[jn] = *(const short8*)(&sA[ab][cL*8]);
            }
            __builtin_amdgcn_s_barrier();
            __builtin_amdgcn_s_setprio(1);
            #pragma unroll
            for (int im = 0; im < 4; ++im)
                #pragma unroll
                for (int jn = 0; jn < 4; ++jn)
                    acc[im][jn + 4] = __builtin_amdgcn_mfma_f32_16x16x32_bf16(bv[im], af[jn], acc[im][jn + 4], 0, 0, 0);
            __builtin_amdgcn_s_setprio(0);

            if (it != 71) {
                if (doB)      asm volatile("s_waitcnt vmcnt(3)" ::: "memory");
                else if (doA) asm volatile("s_waitcnt vmcnt(2)" ::: "memory");
                else          asm volatile("s_waitcnt vmcnt(0)" ::: "memory");
                __builtin_amdgcn_s_barrier();
            }
        }
    }

    // ---- epilogue: bias + relu.  Layout: col(ln)=co, row(kg*4+rg)=hw ----
    float bias[8];
    #pragma unroll
    for (int jn = 0; jn < 8; ++jn)
        bias[jn] = be[e*COUT + wm*128 + jn*16 + ln];
    #pragma unroll
    for (int im = 0; im < 4; ++im)
        #pragma unroll
        for (int jn = 0; jn < 8; ++jn)
            #pragma unroll
            for (int rg = 0; rg < 4; ++rg) {
                float v = acc[im][jn][rg] + bias[jn];
                acc[im][jn][rg] = v > 0.0f ? v : 0.0f;
            }

    // ---- write to every output slot i with dec[i]==e: float4 stores along hw ----
    const volatile int* dv = (const volatile int*)dec;
    for (int i = 0; i < 16; ++i) {
        if (dv[i] != e) continue;
        float* ob = out + (size_t)(i*16 + b)*COUT*HW;
        #pragma unroll
        for (int jn = 0; jn < 8; ++jn) {
            int co = wm*128 + jn*16 + ln;
            float* orow = ob + (size_t)co*HW + ht*256 + wn*64 + kg*4;
            #pragma unroll
            for (int im = 0; im < 4; ++im)
                *(floatx4*)(orow + im*16) = acc[im][jn];
        }
    }
}

extern "C" void kernel_launch(void* const* d_in, const int* in_sizes, int n_in,
                              void* d_out, int out_size, void* d_ws, size_t ws_size,
                              hipStream_t stream) {
    const float* x  = (const float*)d_in[0];
    const float* wc = (const float*)d_in[1];
    const float* bc = (const float*)d_in[2];
    const float* we = (const float*)d_in[3];
    const float* be = (const float*)d_in[4];
    float* out = (float*)d_out;

    char* ws = (char*)d_ws;
    int*   dec    = (int*)ws;
    float* pooled = (float*)(ws + 64);
    unsigned short* xt = (unsigned short*)(ws + XT_OFF);
    unsigned short* wt = (unsigned short*)(ws + WT_OFF);

    // single memset: zeroes dec (overwritten), pooled (accumulated into), and xt halo
    hipMemsetAsync(ws, 0, XT_OFF + XT_BYTES, stream);

    xpose_kernel <<<dim3(16, 32, 8), 256, 0, stream>>>(x, xt, pooled);
    wpose_kernel <<<2048, 256, 0, stream>>>(we, wt);
    decide_kernel<<<1, 128, 0, stream>>>(pooled, wc, bc, dec);
    conv_kernel  <<<dim3(4, 16, 8), 512, 0, stream>>>(xt, wt, be, dec, out);
}

// Round 5
// 481.393 us; speedup vs baseline: 1.1193x; 1.1034x over previous
//
#include <hip/hip_runtime.h>
#include <hip/hip_bf16.h>
#include <stdint.h>

// Problem constants
#define B_    16
#define CIN   256
#define COUT  256
#define E_    8
#define HW    1024   // 32x32
#define PH    34     // padded H (zero halo)
#define PW    34

typedef __attribute__((ext_vector_type(8))) short  short8;
typedef __attribute__((ext_vector_type(4))) float  floatx4;

// Workspace layout (bytes):
//   [0,64)      : (unused)
//   [64,16448)  : pooled float[16*256]  (SUMS; decide scales by 1/1024)
//   [XT_OFF,..) : xt bf16 [16][34][34][256]  (padded NHWC; halo zeroed by prep)
//   [WT_OFF,..) : wt bf16 [8][9][256][256]   ([e][r*3+s][co][ci])
#define XT_OFF 17408
#define XT_BYTES (B_*PH*PW*CIN*2)               // 9,469,952
#define WT_OFF (XT_OFF + XT_BYTES)

// async global->LDS, 16B per lane. LDS dest is wave-uniform base + lane*16.
__device__ __forceinline__ void gld_lds16(const void* g, void* l) {
    __builtin_amdgcn_global_load_lds(
        (const __attribute__((address_space(1))) unsigned int*)g,
        (__attribute__((address_space(3))) unsigned int*)l,
        16, 0, 0);
}

// ---------------- Kernel 1: fused prep ----------------
// bid < 128   : xpose+pool+halo.  block = (b, 32-ci slice); reads x[b, ci0:ci0+32, :]
//               (128 KB, coalesced), writes xt interior bf16 + halo zeros, and the
//               pooled sums via in-wave shuffle reduction (no atomics, no pre-zero).
// bid >= 128  : wpose.  block = (e, co); we [e][co][ci][3][3] -> wt [e][rs][co][ci] bf16.
__global__ void prep_kernel(const float* __restrict__ x, const float* __restrict__ we,
                            unsigned short* __restrict__ xt, unsigned short* __restrict__ wt,
                            float* __restrict__ pooled) {
    int bid = blockIdx.x;
    int t = threadIdx.x;
    if (bid < 128) {
        int b = bid >> 3, ci0 = (bid & 7) * 32;
        __shared__ float tileF[32][65];        // +1 pad: write banks (ci+hwl)%32, read 2-way max
        float psum[8];
        #pragma unroll
        for (int li = 0; li < 8; ++li) psum[li] = 0.0f;
        int hwl = t & 63, wv = t >> 6;         // load coords: wave wv owns ci = wv + 4*li
        int hwl2 = t >> 2, grp = t & 3;        // store coords: 64 hw x 4 ci-groups of 8
        for (int chunk = 0; chunk < 16; ++chunk) {
            #pragma unroll
            for (int li = 0; li < 8; ++li) {
                int ci = wv + li*4;
                float v = x[((size_t)b*CIN + ci0 + ci)*HW + chunk*64 + hwl];
                tileF[ci][hwl] = v;
                psum[li] += v;
            }
            __syncthreads();
            int hw = chunk*64 + hwl2;
            int h = hw >> 5, w = hw & 31;
            short8 v8;
            #pragma unroll
            for (int q = 0; q < 8; ++q) {
                __hip_bfloat16 hv = __float2bfloat16(tileF[grp*8 + q][hwl2]);
                v8[q] = *(short*)&hv;
            }
            *(short8*)&xt[(((size_t)b*PH + h + 1)*PW + (w + 1))*CIN + ci0 + grp*8] = v8;
            __syncthreads();                   // before next chunk overwrites tileF
        }
        // pool: full-wave reduce each of the 8 ci rows this wave owns
        #pragma unroll
        for (int li = 0; li < 8; ++li) {
            float s = psum[li];
            #pragma unroll
            for (int o = 32; o > 0; o >>= 1) s += __shfl_down(s, o, 64);
            if ((t & 63) == 0) pooled[b*CIN + ci0 + wv + li*4] = s;
        }
        // halo zeros for this (b, ci slice): 132 border positions x 4 ci-groups
        short8 z = {0,0,0,0,0,0,0,0};
        for (int idx = t; idx < 528; idx += 256) {
            int pos = idx >> 2, sub = idx & 3;
            int h, w;
            if (pos < 34)       { h = 0;            w = pos; }
            else if (pos < 68)  { h = 33;           w = pos - 34; }
            else if (pos < 100) { h = pos - 68 + 1; w = 0; }
            else                { h = pos - 100 + 1;w = 33; }
            *(short8*)&xt[(((size_t)b*PH + h)*PW + w)*CIN + ci0 + sub*8] = z;
        }
    } else {
        int wbid = bid - 128;
        int e = wbid >> 8, co = wbid & 255;
        __shared__ float buf[CIN*9];
        const float* src = we + ((size_t)e*COUT + co)*CIN*9;
        #pragma unroll
        for (int k = 0; k < 9; ++k) buf[t + k*256] = src[t + k*256];
        __syncthreads();
        for (int idx = t; idx < 288; idx += 256) {
            int rs = idx >> 5, grp = idx & 31;
            short8 v;
            #pragma unroll
            for (int q = 0; q < 8; ++q) {
                __hip_bfloat16 h = __float2bfloat16(buf[(grp*8 + q)*9 + rs]);
                v[q] = *(short*)&h;
            }
            *(short8*)&wt[(((size_t)e*9 + rs)*COUT + co)*CIN + grp*8] = v;
        }
    }
}

// ---------------- Kernel 2: conv (R0 structure) + in-kernel decide + gather-write ----------
// Double-buffered, software-pipelined, XOR-bank-swizzled — the best-measured structure
// (212 us).  Decisions computed in-kernel from pooled sums (deterministic, identical in
// every block).  MFMA operands swapped (rows=hw) so the epilogue stores are float4.
// grid: x = mt*8+nt (16 tiles of the 256x1024 output), y = b (16), z = e (8); 256 threads
__global__ __launch_bounds__(256) void conv_kernel(
    const unsigned short* __restrict__ xt, const unsigned short* __restrict__ wt,
    const float* __restrict__ pooled, const float* __restrict__ wc,
    const float* __restrict__ bc, const float* __restrict__ be,
    float* __restrict__ out) {

    int tile = blockIdx.x;
    int b = blockIdx.y;
    int e = blockIdx.z;
    int mt = tile >> 3, nt = tile & 7;
    int t = threadIdx.x;

    // ---- in-kernel decide (replaces the decide dispatch) ----
    __shared__ float lg[16][8];
    __shared__ int sdec[16];
    if (t < 128) {
        int bb = t >> 3, ee = t & 7;
        float acc = 0.0f;
        const float4* pp = (const float4*)(pooled + bb*CIN);
        const float4* ww = (const float4*)(wc + ee*CIN);
        #pragma unroll 4
        for (int i = 0; i < CIN/4; ++i) {
            float4 p = pp[i], w = ww[i];
            acc += p.x*w.x + p.y*w.y + p.z*w.z + p.w*w.w;
        }
        lg[bb][ee] = acc * (1.0f/1024.0f) + bc[ee];   // pooled holds sums
    }
    __syncthreads();
    if (t < 16) {
        float best = lg[t][0]; int bi = 0;
        #pragma unroll
        for (int j = 1; j < 8; ++j) if (lg[t][j] > best) { best = lg[t][j]; bi = j; }
        sdec[t] = bi;
    }
    __syncthreads();
    int dcs[16];
    #pragma unroll
    for (int i = 0; i < 16; ++i) dcs[i] = sdec[i];
    bool active = false;
    #pragma unroll
    for (int i = 0; i < 16; ++i) active |= (dcs[i] == e);
    if (!active) return;   // uniform across block

    // Chunk-addressed LDS (16 B chunks), XOR-swizzled: global chunk (row, g)
    // lives at LDS chunk row*4 + (g ^ ((row>>1)&3)).  Involutive.
    // sA[2]: 512 chunks each (A tile 128 co x 4 ci-chunks), 8 KB each.
    // sB[2]: 1024 chunks each (816 live: 6x34 halo rows x 4 ci-chunks), 16 KB each.
    __shared__ __align__(16) unsigned short sA[2][512*8];
    __shared__ __align__(16) unsigned short sB[2][1024*8];

    int wave = t >> 6, lane = t & 63;
    int wm = wave >> 1, wn = wave & 1;     // 2x2 wave grid, 64x64 per wave
    int kg = lane >> 4, ln = lane & 15;

    int ph0 = nt * 4;       // padded halo start row
    int co0 = mt * 128;

    floatx4 acc[4][4];
    #pragma unroll
    for (int i = 0; i < 4; ++i)
        #pragma unroll
        for (int j = 0; j < 4; ++j) acc[i][j] = (floatx4)0.0f;

    const unsigned short* xb = xt + ((size_t)b*PH + ph0)*PW*CIN;   // halo base (6x34 rows)
    const unsigned short* wb = wt + (size_t)e*9*COUT*CIN + (size_t)co0*CIN;

    auto stageA = [&](int ck, int sh, int buf) {
        const unsigned short* wsrc = wb + (size_t)sh*COUT*CIN + ck*32;
        #pragma unroll
        for (int k = 0; k < 2; ++k) {
            int c = t + k*256;
            int row = c >> 2, gs = c & 3;
            int g = gs ^ ((row >> 1) & 3);
            gld_lds16(wsrc + (size_t)row*CIN + g*8, &sA[buf][c*8]);
        }
    };
    auto stageB = [&](int ck, int buf) {
        const unsigned short* xsrc = xb + ck*32;
        #pragma unroll
        for (int k = 0; k < 3; ++k) {
            int c = t + k*256;
            int rB = c >> 2, gs = c & 3;
            int g = gs ^ ((rB >> 1) & 3);
            gld_lds16(xsrc + (size_t)rB*CIN + g*8, &sB[buf][c*8]);
        }
        if (t < 64) {                     // wave 0: chunks 768..831 (816..831 dead-clamped)
            int c = t + 768;
            int cc = c < 816 ? c : 815;
            int rB = cc >> 2, gs = cc & 3;
            int g = gs ^ ((rB >> 1) & 3);
            gld_lds16(xsrc + (size_t)rB*CIN + g*8, &sB[buf][c*8]);
        }
    };

    // ---- prologue: stage iteration 0 ----
    stageB(0, 0);
    stageA(0, 0, 0);
    __syncthreads();

    // ---- main loop: it = ck*9+sh; sA parity = it&1, sB parity = ck&1 ----
    for (int ck = 0; ck < 8; ++ck) {
        for (int sh = 0; sh < 9; ++sh) {
            int it = ck*9 + sh;
            int ab = it & 1, bb_ = ck & 1;

            // prefetch next iteration's tiles into the alternate buffers
            if (sh < 8) {
                stageA(ck, sh + 1, ab ^ 1);
            } else if (ck < 7) {
                stageA(ck + 1, 0, ab ^ 1);
                stageB(ck + 1, bb_ ^ 1);
            }

            // frag reads (swizzled)
            short8 a[4], bv[4];
            #pragma unroll
            for (int im = 0; im < 4; ++im) {
                int row = wm*64 + im*16 + ln;
                int cL = row*4 + (kg ^ ((row >> 1) & 3));
                a[im] = *(const short8*)(&sA[ab][cL*8]);
            }
            int r = sh / 3, s = sh - r*3;
            #pragma unroll
            for (int in = 0; in < 4; ++in) {
                int n  = wn*64 + in*16 + ln;
                int hl = n >> 5, wl = n & 31;
                int rB = (hl + r)*34 + (wl + s);
                int cL = rB*4 + (kg ^ ((rB >> 1) & 3));
                bv[in] = *(const short8*)(&sB[bb_][cL*8]);
            }

            // swapped operands: C rows = hw (bv), cols = co (a)  [verified passing in R1]
            #pragma unroll
            for (int im = 0; im < 4; ++im)
                #pragma unroll
                for (int in = 0; in < 4; ++in)
                    acc[im][in] = __builtin_amdgcn_mfma_f32_16x16x32_bf16(bv[in], a[im], acc[im][in], 0, 0, 0);

            // single barrier: frag reads of current buffers done + prefetch DMA complete
            __syncthreads();
        }
    }

    // ---- epilogue: bias + relu.  Layout: col(ln)=co, row(kg*4+rg)=hw ----
    float bias[4];
    #pragma unroll
    for (int im = 0; im < 4; ++im)
        bias[im] = be[e*COUT + co0 + wm*64 + im*16 + ln];
    #pragma unroll
    for (int im = 0; im < 4; ++im)
        #pragma unroll
        for (int in = 0; in < 4; ++in)
            #pragma unroll
            for (int rg = 0; rg < 4; ++rg) {
                float v = acc[im][in][rg] + bias[im];
                acc[im][in][rg] = v > 0.0f ? v : 0.0f;
            }

    // ---- write to every output slot i with dec[i]==e: float4 stores along hw ----
    for (int i = 0; i < 16; ++i) {
        if (dcs[i] != e) continue;
        float* ob = out + (size_t)(i*16 + b)*COUT*HW;
        #pragma unroll
        for (int im = 0; im < 4; ++im) {
            int co = co0 + wm*64 + im*16 + ln;
            float* orow = ob + (size_t)co*HW + nt*128 + wn*64 + kg*4;
            #pragma unroll
            for (int in = 0; in < 4; ++in)
                *(floatx4*)(orow + in*16) = acc[im][in];
        }
    }
}

extern "C" void kernel_launch(void* const* d_in, const int* in_sizes, int n_in,
                              void* d_out, int out_size, void* d_ws, size_t ws_size,
                              hipStream_t stream) {
    const float* x  = (const float*)d_in[0];
    const float* wc = (const float*)d_in[1];
    const float* bc = (const float*)d_in[2];
    const float* we = (const float*)d_in[3];
    const float* be = (const float*)d_in[4];
    float* out = (float*)d_out;

    char* ws = (char*)d_ws;
    float* pooled = (float*)(ws + 64);
    unsigned short* xt = (unsigned short*)(ws + XT_OFF);
    unsigned short* wt = (unsigned short*)(ws + WT_OFF);

    // Two dispatches total.  No memset: prep writes pooled fully (no accumulation),
    // xt fully (interior + halo), wt fully.
    prep_kernel<<<2176, 256, 0, stream>>>(x, we, xt, wt, pooled);
    conv_kernel<<<dim3(16, 16, 8), 256, 0, stream>>>(xt, wt, pooled, wc, bc, be, out);
}